// Round 5
// baseline (447.126 us; speedup 1.0000x reference)
//
#include <hip/hip_runtime.h>
#include <hip/hip_cooperative_groups.h>

namespace cg = cooperative_groups;

#define NF 128
#define OUTF 64

// mark bits
#define M2 1   // x2 needed (layer-2 frontier)
#define M1 2   // x1 needed (layer-1 frontier)
#define M0 4   // x0 needed (rows for GEMM1)

// capacity caps (measured cone: ~13 / ~180 / ~2600 nodes; huge slack)
#define CAP_F2 2048
#define CAP_E3 4096
#define CAP_F1 32768
#define CAP_E2 65536
#define CAP_F0 131072
#define CAP_E1 262144

// cnt[0]=F2, cnt[1]=E3, cnt[2]=F1, cnt[3]=E2, cnt[4]=F0, cnt[5]=E1

struct Params {
    const float* x; const int* src; const int* dst; int E; int n; int last;
    const float* W1; const float* b1; const float* W2; const float* b2;
    const float* W3; const float* b3; const float* fcW; const float* fcb;
    int* deg; int* mark; int* cnt;
    int* F2; int2* E3l; int* F1; int2* E2l; int* F0; int2* E1l;
    float* H; float* aggA; float* aggB; float* out;
};

__device__ __forceinline__ float dinv_of(const int* deg, int v) {
    return rsqrtf(1.0f + (float)deg[v]);
}

__global__ __launch_bounds__(256) void k_fused(Params p) {
    cg::grid_group grid = cg::this_grid();
    __shared__ float wsm[128][128];   // 64 KB: W tile per gemm phase, xrow in fc

    const int t       = threadIdx.x;
    const int gtid    = blockIdx.x * 256 + t;
    const int gstride = gridDim.x * 256;
    const int last    = p.last;

    // ---- P0: zero deg/mark, init cnt, seed F2={last} ----
    for (int i = gtid; i < p.n; i += gstride) {
        p.deg[i]  = 0;
        p.mark[i] = (i == last) ? M2 : 0;
    }
    if (gtid < 64) p.cnt[gtid] = (gtid == 0) ? 1 : 0;
    if (gtid == 0) p.F2[0] = last;
    grid.sync();

    // ---- P1: BFS level 1 (edges into last) + full degree histogram ----
    for (int i = gtid; i < p.E; i += gstride) {
        int d = p.dst[i];
        atomicAdd(&p.deg[d], 1);
        if (d == last) {
            int s = p.src[i];
            int pe = atomicAdd(&p.cnt[1], 1);
            if (pe < CAP_E3) p.E3l[pe] = make_int2(s, d);
            if (!(atomicOr(&p.mark[s], M2) & M2)) {
                int q = atomicAdd(&p.cnt[0], 1);
                if (q < CAP_F2) p.F2[q] = s;
            }
        }
    }
    grid.sync();

    // ---- P2: BFS level 2: F2 self-prop into F1 + edges into M2 nodes ----
    {
        int sc = p.cnt[0]; if (sc > CAP_F2) sc = CAP_F2;
        for (int i = gtid; i < sc; i += gstride) {
            int v = p.F2[i];
            if (!(atomicOr(&p.mark[v], M1) & M1)) {
                int q = atomicAdd(&p.cnt[2], 1);
                if (q < CAP_F1) p.F1[q] = v;
            }
        }
        for (int i = gtid; i < p.E; i += gstride) {
            int d = p.dst[i];
            if (p.mark[d] & M2) {            // M2 bits finalized in P1
                int s = p.src[i];
                int pe = atomicAdd(&p.cnt[3], 1);
                if (pe < CAP_E2) p.E2l[pe] = make_int2(s, d);
                if (!(atomicOr(&p.mark[s], M1) & M1)) {
                    int q = atomicAdd(&p.cnt[2], 1);
                    if (q < CAP_F1) p.F1[q] = s;
                }
            }
        }
    }
    grid.sync();

    // ---- P3: BFS level 3: F1 self-prop into F0 + edges into M1 nodes ----
    {
        int sc = p.cnt[2]; if (sc > CAP_F1) sc = CAP_F1;
        for (int i = gtid; i < sc; i += gstride) {
            int v = p.F1[i];
            if (!(atomicOr(&p.mark[v], M0) & M0)) {
                int q = atomicAdd(&p.cnt[4], 1);
                if (q < CAP_F0) p.F0[q] = v;
            }
        }
        for (int i = gtid; i < p.E; i += gstride) {
            int d = p.dst[i];
            if (p.mark[d] & M1) {            // M1 bits finalized in P2
                int s = p.src[i];
                int pe = atomicAdd(&p.cnt[5], 1);
                if (pe < CAP_E1) p.E1l[pe] = make_int2(s, d);
                if (!(atomicOr(&p.mark[s], M0) & M0)) {
                    int q = atomicAdd(&p.cnt[4], 1);
                    if (q < CAP_F0) p.F0[q] = s;
                }
            }
        }
    }
    grid.sync();

    // counts (finalized)
    int cF2 = p.cnt[0]; if (cF2 > CAP_F2) cF2 = CAP_F2;
    int cE3 = p.cnt[1]; if (cE3 > CAP_E3) cE3 = CAP_E3;
    int cF1 = p.cnt[2]; if (cF1 > CAP_F1) cF1 = CAP_F1;
    int cE2 = p.cnt[3]; if (cE2 > CAP_E2) cE2 = CAP_E2;
    int cF0 = p.cnt[4]; if (cF0 > CAP_F0) cF0 = CAP_F0;
    int cE1 = p.cnt[5]; if (cE1 > CAP_E1) cE1 = CAP_E1;

    const int wave = t >> 6, lane = t & 63;

    // gemm phase: for v in list: xr = bias? relu(Xin[v]+bias) : Xin[v];
    // H[v] = xr @ W; if (agg condition) AGG[v] = dinv[v]^2 * H[v].
    auto gemm = [&](const int* list, int cntv, const float* Xin, const float* bias,
                    const float* Wg, int aggBit, float* H, float* AGG) {
        const float4* W4 = (const float4*)Wg;
        float4* S4 = (float4*)&wsm[0][0];
        #pragma unroll
        for (int it = 0; it < 16; ++it) S4[it * 256 + t] = W4[it * 256 + t];
        __syncthreads();

        for (int r = blockIdx.x * 4 + wave; r < cntv; r += gridDim.x * 4) {
            int v = list[r];
            size_t off = (size_t)v * NF;
            float x0, x1;
            if (bias) {
                x0 = fmaxf(Xin[off + lane]      + bias[lane],      0.f);
                x1 = fmaxf(Xin[off + lane + 64] + bias[lane + 64], 0.f);
            } else {
                x0 = Xin[off + lane];
                x1 = Xin[off + lane + 64];
            }
            float a0 = 0.f, a1 = 0.f;
            #pragma unroll 16
            for (int k = 0; k < 64; ++k) {
                float xk = __shfl(x0, k);
                a0 += xk * wsm[k][lane];
                a1 += xk * wsm[k][lane + 64];
            }
            #pragma unroll 16
            for (int k = 0; k < 64; ++k) {
                float xk = __shfl(x1, k);
                a0 += xk * wsm[k + 64][lane];
                a1 += xk * wsm[k + 64][lane + 64];
            }
            H[off + lane]      = a0;
            H[off + lane + 64] = a1;

            bool doAgg = aggBit ? ((p.mark[v] & aggBit) != 0) : (v == last);
            if (doAgg) {
                float di = dinv_of(p.deg, v);
                float s2 = di * di;
                AGG[off + lane]      = a0 * s2;
                AGG[off + lane + 64] = a1 * s2;
            }
        }
    };

    // scatter phase: AGG[d] += dinv[s]*dinv[d] * H[s] over edge list
    auto scat = [&](const int2* El, int ec, const float* H, float* AGG) {
        int half = t >> 7;          // 2 edges per block-iteration
        int f    = t & 127;
        for (int i = blockIdx.x * 2 + half; i < ec; i += gridDim.x * 2) {
            int2 e = El[i];
            float w = dinv_of(p.deg, e.x) * dinv_of(p.deg, e.y);
            atomicAdd(&AGG[(size_t)e.y * NF + f], H[(size_t)e.x * NF + f] * w);
        }
    };

    // ---- layer 1: H = x@W1 on F0; agg init on M1 rows; scatter E1 ----
    gemm(p.F0, cF0, p.x, nullptr, p.W1, M1, p.H, p.aggA);
    grid.sync();
    scat(p.E1l, cE1, p.H, p.aggA);
    grid.sync();

    // ---- layer 2: H = relu(agg1+b1)@W2 on F1; agg init on M2 rows; scatter E2 ----
    gemm(p.F1, cF1, p.aggA, p.b1, p.W2, M2, p.H, p.aggB);
    grid.sync();
    scat(p.E2l, cE2, p.H, p.aggB);
    grid.sync();

    // ---- layer 3: H = relu(agg2+b2)@W3 on F2; agg init on {last}; scatter E3 ----
    gemm(p.F2, cF2, p.aggB, p.b2, p.W3, 0, p.H, p.aggA);
    grid.sync();
    scat(p.E3l, cE3, p.H, p.aggA);
    grid.sync();

    // ---- fc: out = relu(aggA[last]+b3) @ fcW + fcb ----
    if (blockIdx.x == 0) {
        float* xrow = &wsm[0][0];
        size_t off = (size_t)last * NF;
        if (t < 64) {
            xrow[t]      = fmaxf(p.aggA[off + t]      + p.b3[t],      0.f);
            xrow[t + 64] = fmaxf(p.aggA[off + t + 64] + p.b3[t + 64], 0.f);
        }
        __syncthreads();
        if (t < 64) {
            float acc = p.fcb[t];
            #pragma unroll 16
            for (int k = 0; k < NF; ++k) acc += xrow[k] * p.fcW[k * OUTF + t];
            p.out[t] = acc;
        }
    }
}

extern "C" void kernel_launch(void* const* d_in, const int* in_sizes, int n_in,
                              void* d_out, int out_size, void* d_ws, size_t ws_size,
                              hipStream_t stream)
{
    const int n = in_sizes[0] / NF;       // 50000
    const int E = in_sizes[1] / 2;        // 600000

    char* wp = (char*)d_ws;
    auto alloc = [&](size_t bytes) -> void* {
        void* r = (void*)wp;
        wp += (bytes + 255) & ~(size_t)255;
        return r;
    };

    Params p;
    p.x    = (const float*)d_in[0];
    p.src  = (const int*)d_in[1];
    p.dst  = (const int*)d_in[1] + E;
    p.E    = E;
    p.n    = n;
    p.last = n - 1;
    p.W1   = (const float*)d_in[2];
    p.b1   = (const float*)d_in[3];
    p.W2   = (const float*)d_in[4];
    p.b2   = (const float*)d_in[5];
    p.W3   = (const float*)d_in[6];
    p.b3   = (const float*)d_in[7];
    p.fcW  = (const float*)d_in[8];
    p.fcb  = (const float*)d_in[9];

    p.deg  = (int*)  alloc((size_t)n * 4);
    p.mark = (int*)  alloc((size_t)n * 4);
    p.cnt  = (int*)  alloc(64 * 4);
    p.F2   = (int*)  alloc(CAP_F2 * 4);
    p.E3l  = (int2*) alloc(CAP_E3 * 8);
    p.F1   = (int*)  alloc(CAP_F1 * 4);
    p.E2l  = (int2*) alloc(CAP_E2 * 8);
    p.F0   = (int*)  alloc(CAP_F0 * 4);
    p.E1l  = (int2*) alloc(CAP_E1 * 8);
    p.H    = (float*)alloc((size_t)n * NF * 4);
    p.aggA = (float*)alloc((size_t)n * NF * 4);
    p.aggB = (float*)alloc((size_t)n * NF * 4);
    p.out  = (float*)d_out;

    void* args[] = { &p };
    hipLaunchCooperativeKernel((const void*)k_fused, dim3(256), dim3(256),
                               args, 0, stream);
}

// Round 7
// 446.719 us; speedup vs baseline: 1.0009x; 1.0009x over previous
//
#include <hip/hip_runtime.h>

#define NF 128
#define OUTF 64

// mark bits
#define M2 1   // layer-2 frontier (x2 needed)
#define M1 2   // layer-1 frontier (x1 needed)
#define M0 4   // rows for GEMM1 (x0 needed)

// capacity caps (measured cone: ~13 / ~180 / ~2600 nodes; big slack)
#define CAP_F2 2048
#define CAP_E3 4096
#define CAP_F1 32768
#define CAP_E2 65536
#define CAP_F0 131072
#define CAP_E1 262144

#define NBLK 128   // 64 KB LDS -> 2 blocks/CU; 128 blocks on 256 CUs co-resident

// cnt[0]=F2, cnt[1]=E3, cnt[2]=F1, cnt[3]=E2, cnt[4]=F0, cnt[5]=E1
// cnt[8]=barrier arrival, cnt[9]=barrier generation

struct Params {
    const float* x; const int* src; const int* dst; int E; int n; int last;
    const float* W1; const float* b1; const float* W2; const float* b2;
    const float* W3; const float* b3; const float* fcW; const float* fcb;
    int* deg; int* mark; int* cnt;
    int* F2; int2* E3l; int* F1; int2* E2l; int* F0; int2* E1l;
    float* H; float* aggA; float* aggB; float* out;
};

__device__ __forceinline__ int aload(const int* p) {
    return __hip_atomic_load(p, __ATOMIC_RELAXED, __HIP_MEMORY_SCOPE_AGENT);
}

__device__ __forceinline__ float dinv_of(const int* deg, int v) {
    return rsqrtf(1.0f + (float)aload(&deg[v]));
}

// Grid barrier. All threads fence on both sides (release: own stores drained
// + L2 writeback; acquire: invalidate stale lines). Thread 0 arrives/spins.
__device__ __forceinline__ void gbar(int* bar, int* gen) {
    __threadfence();                 // release side, every wave
    __syncthreads();
    if (threadIdx.x == 0) {
        int g = __hip_atomic_load(gen, __ATOMIC_RELAXED, __HIP_MEMORY_SCOPE_AGENT);
        int a = __hip_atomic_fetch_add(bar, 1, __ATOMIC_ACQ_REL, __HIP_MEMORY_SCOPE_AGENT);
        if (a == NBLK - 1) {
            __hip_atomic_store(bar, 0, __ATOMIC_RELAXED, __HIP_MEMORY_SCOPE_AGENT);
            __hip_atomic_fetch_add(gen, 1, __ATOMIC_RELEASE, __HIP_MEMORY_SCOPE_AGENT);
        } else {
            while (__hip_atomic_load(gen, __ATOMIC_ACQUIRE, __HIP_MEMORY_SCOPE_AGENT) == g)
                __builtin_amdgcn_s_sleep(1);
        }
    }
    __syncthreads();
    __threadfence();                 // acquire side, every wave
}

__global__ __launch_bounds__(256) void k_tail(Params p) {
    __shared__ float wsm[128][128];   // 64 KB: W tile in gemm phases, xrow in fc

    const int t       = threadIdx.x;
    const int gtid    = blockIdx.x * 256 + t;
    const int gstride = gridDim.x * 256;
    const int last    = p.last;
    int* bar = &p.cnt[8];
    int* gen = &p.cnt[9];

    // ---- P1: full degree histogram + BFS level 1 (edges into last) ----
    // deg/mark/cnt pre-zeroed by memset. Seed goes through the SAME atomic
    // append path as edge-discovered nodes (no plain stores -> no race).
    if (gtid == 0) {
        if (!(atomicOr(&p.mark[last], M2) & M2)) {
            int q = atomicAdd(&p.cnt[0], 1);
            if (q < CAP_F2) p.F2[q] = last;
        }
    }
    for (int i = gtid; i < p.E; i += gstride) {
        int d = p.dst[i];
        atomicAdd(&p.deg[d], 1);
        if (d == last) {
            int s = p.src[i];
            int pe = atomicAdd(&p.cnt[1], 1);
            if (pe < CAP_E3) p.E3l[pe] = make_int2(s, d);
            if (!(atomicOr(&p.mark[s], M2) & M2)) {
                int q = atomicAdd(&p.cnt[0], 1);
                if (q < CAP_F2) p.F2[q] = s;
            }
        }
    }
    gbar(bar, gen);

    // ---- P2: F2 self-prop into F1 + edges into M2 nodes -> E2, F1 ----
    {
        int sc = aload(&p.cnt[0]); if (sc > CAP_F2) sc = CAP_F2;
        for (int i = gtid; i < sc; i += gstride) {
            int v = p.F2[i];
            if (!(atomicOr(&p.mark[v], M1) & M1)) {
                int q = atomicAdd(&p.cnt[2], 1);
                if (q < CAP_F1) p.F1[q] = v;
            }
        }
        for (int i = gtid; i < p.E; i += gstride) {
            int d = p.dst[i];
            if (aload(&p.mark[d]) & M2) {     // M2 bits finalized at P1 barrier
                int s = p.src[i];
                int pe = atomicAdd(&p.cnt[3], 1);
                if (pe < CAP_E2) p.E2l[pe] = make_int2(s, d);
                if (!(atomicOr(&p.mark[s], M1) & M1)) {
                    int q = atomicAdd(&p.cnt[2], 1);
                    if (q < CAP_F1) p.F1[q] = s;
                }
            }
        }
    }
    gbar(bar, gen);

    // ---- P3: F1 self-prop into F0 + edges into M1 nodes -> E1, F0 ----
    {
        int sc = aload(&p.cnt[2]); if (sc > CAP_F1) sc = CAP_F1;
        for (int i = gtid; i < sc; i += gstride) {
            int v = p.F1[i];
            if (!(atomicOr(&p.mark[v], M0) & M0)) {
                int q = atomicAdd(&p.cnt[4], 1);
                if (q < CAP_F0) p.F0[q] = v;
            }
        }
        for (int i = gtid; i < p.E; i += gstride) {
            int d = p.dst[i];
            if (aload(&p.mark[d]) & M1) {     // M1 bits finalized at P2 barrier
                int s = p.src[i];
                int pe = atomicAdd(&p.cnt[5], 1);
                if (pe < CAP_E1) p.E1l[pe] = make_int2(s, d);
                if (!(atomicOr(&p.mark[s], M0) & M0)) {
                    int q = atomicAdd(&p.cnt[4], 1);
                    if (q < CAP_F0) p.F0[q] = s;
                }
            }
        }
    }
    gbar(bar, gen);

    int cF2 = aload(&p.cnt[0]); if (cF2 > CAP_F2) cF2 = CAP_F2;
    int cE3 = aload(&p.cnt[1]); if (cE3 > CAP_E3) cE3 = CAP_E3;
    int cF1 = aload(&p.cnt[2]); if (cF1 > CAP_F1) cF1 = CAP_F1;
    int cE2 = aload(&p.cnt[3]); if (cE2 > CAP_E2) cE2 = CAP_E2;
    int cF0 = aload(&p.cnt[4]); if (cF0 > CAP_F0) cF0 = CAP_F0;
    int cE1 = aload(&p.cnt[5]); if (cE1 > CAP_E1) cE1 = CAP_E1;

    const int wave = t >> 6, lane = t & 63;

    // gemm: for v in list: xr = bias? relu(Xin[v]+bias) : Xin[v]; H[v]=xr@W;
    // if (mark[v]&aggBit) or (aggBit==0 && v==last): AGG[v] = dinv^2 * H[v].
    auto gemm = [&](const int* list, int cntv, const float* Xin, const float* bias,
                    const float* Wg, int aggBit, float* H, float* AGG) {
        const float4* W4 = (const float4*)Wg;
        float4* S4 = (float4*)&wsm[0][0];
        #pragma unroll
        for (int it = 0; it < 16; ++it) S4[it * 256 + t] = W4[it * 256 + t];
        __syncthreads();

        for (int r = blockIdx.x * 4 + wave; r < cntv; r += gridDim.x * 4) {
            int v = list[r];
            size_t off = (size_t)v * NF;
            float x0, x1;
            if (bias) {
                x0 = fmaxf(Xin[off + lane]      + bias[lane],      0.f);
                x1 = fmaxf(Xin[off + lane + 64] + bias[lane + 64], 0.f);
            } else {
                x0 = Xin[off + lane];
                x1 = Xin[off + lane + 64];
            }
            float a0 = 0.f, a1 = 0.f;
            #pragma unroll 16
            for (int k = 0; k < 64; ++k) {
                float xk = __shfl(x0, k);
                a0 += xk * wsm[k][lane];
                a1 += xk * wsm[k][lane + 64];
            }
            #pragma unroll 16
            for (int k = 0; k < 64; ++k) {
                float xk = __shfl(x1, k);
                a0 += xk * wsm[k + 64][lane];
                a1 += xk * wsm[k + 64][lane + 64];
            }
            H[off + lane]      = a0;
            H[off + lane + 64] = a1;

            bool doAgg = aggBit ? ((aload(&p.mark[v]) & aggBit) != 0) : (v == last);
            if (doAgg) {
                float di = dinv_of(p.deg, v);
                float s2 = di * di;
                AGG[off + lane]      = a0 * s2;
                AGG[off + lane + 64] = a1 * s2;
            }
        }
        __syncthreads();   // protect wsm before any later restage
    };

    // scatter: AGG[d] += dinv[s]*dinv[d] * H[s] over edge list
    auto scat = [&](const int2* El, int ec, const float* H, float* AGG) {
        int half = t >> 7;
        int f    = t & 127;
        for (int i = blockIdx.x * 2 + half; i < ec; i += gridDim.x * 2) {
            int2 e = El[i];
            float w = dinv_of(p.deg, e.x) * dinv_of(p.deg, e.y);
            atomicAdd(&AGG[(size_t)e.y * NF + f], H[(size_t)e.x * NF + f] * w);
        }
    };

    // ---- layer 1 ----
    gemm(p.F0, cF0, p.x, nullptr, p.W1, M1, p.H, p.aggA);
    gbar(bar, gen);
    scat(p.E1l, cE1, p.H, p.aggA);
    gbar(bar, gen);

    // ---- layer 2 ----
    gemm(p.F1, cF1, p.aggA, p.b1, p.W2, M2, p.H, p.aggB);
    gbar(bar, gen);
    scat(p.E2l, cE2, p.H, p.aggB);
    gbar(bar, gen);

    // ---- layer 3 ----
    gemm(p.F2, cF2, p.aggB, p.b2, p.W3, 0, p.H, p.aggA);
    gbar(bar, gen);
    scat(p.E3l, cE3, p.H, p.aggA);
    gbar(bar, gen);

    // ---- fc: out = relu(aggA[last]+b3) @ fcW + fcb ----
    if (blockIdx.x == 0) {
        float* xrow = &wsm[0][0];
        size_t off = (size_t)last * NF;
        if (t < 64) {
            xrow[t]      = fmaxf(p.aggA[off + t]      + p.b3[t],      0.f);
            xrow[t + 64] = fmaxf(p.aggA[off + t + 64] + p.b3[t + 64], 0.f);
        }
        __syncthreads();
        if (t < 64) {
            float acc = p.fcb[t];
            #pragma unroll 16
            for (int k = 0; k < NF; ++k) acc += xrow[k] * p.fcW[k * OUTF + t];
            p.out[t] = acc;
        }
    }
}

extern "C" void kernel_launch(void* const* d_in, const int* in_sizes, int n_in,
                              void* d_out, int out_size, void* d_ws, size_t ws_size,
                              hipStream_t stream)
{
    const int n = in_sizes[0] / NF;       // 50000
    const int E = in_sizes[1] / 2;        // 600000

    char* wp = (char*)d_ws;
    auto alloc = [&](size_t bytes) -> void* {
        void* r = (void*)wp;
        wp += (bytes + 255) & ~(size_t)255;
        return r;
    };

    Params p;
    p.x    = (const float*)d_in[0];
    p.src  = (const int*)d_in[1];
    p.dst  = (const int*)d_in[1] + E;
    p.E    = E;
    p.n    = n;
    p.last = n - 1;
    p.W1   = (const float*)d_in[2];
    p.b1   = (const float*)d_in[3];
    p.W2   = (const float*)d_in[4];
    p.b2   = (const float*)d_in[5];
    p.W3   = (const float*)d_in[6];
    p.b3   = (const float*)d_in[7];
    p.fcW  = (const float*)d_in[8];
    p.fcb  = (const float*)d_in[9];

    // zeroed region: deg | mark | cnt  (one memset)
    p.deg  = (int*)  alloc((size_t)n * 4);
    p.mark = (int*)  alloc((size_t)n * 4);
    p.cnt  = (int*)  alloc(64 * 4);
    size_t zbytes = (char*)wp - (char*)p.deg;

    p.F2   = (int*)  alloc(CAP_F2 * 4);
    p.E3l  = (int2*) alloc(CAP_E3 * 8);
    p.F1   = (int*)  alloc(CAP_F1 * 4);
    p.E2l  = (int2*) alloc(CAP_E2 * 8);
    p.F0   = (int*)  alloc(CAP_F0 * 4);
    p.E1l  = (int2*) alloc(CAP_E1 * 8);
    p.H    = (float*)alloc((size_t)n * NF * 4);
    p.aggA = (float*)alloc((size_t)n * NF * 4);
    p.aggB = (float*)alloc((size_t)n * NF * 4);
    p.out  = (float*)d_out;

    hipMemsetAsync(p.deg, 0, zbytes, stream);
    k_tail<<<NBLK, 256, 0, stream>>>(p);
}

// Round 8
// 381.578 us; speedup vs baseline: 1.1718x; 1.1707x over previous
//
#include <hip/hip_runtime.h>

#define NF 128
#define OUTF 64

// mark bits
#define M2 1   // layer-2 frontier (x2 needed): last + its in-neighbors
#define M1 2   // layer-1 frontier (x1 needed): M2 nodes + their in-neighbors

// capacity caps (measured cone ~13 M2-nodes / ~180 M1-nodes; big slack)
#define CAP_F2 4096
#define CAP_E3 8192
#define CAP_F1 65536
#define CAP_E2 131072

// cnt[0]=F2, cnt[1]=E3, cnt[2]=F1, cnt[3]=E2

__device__ __forceinline__ float dinv_of(const int* deg, int v) {
    return rsqrtf(1.0f + (float)deg[v]);
}

// ---- k_mark1: full in-degree histogram + BFS level 1 (edges into last) ----
// deg/mark/cnt pre-zeroed. Seed of `last` goes through the same atomic path.
__global__ void k_mark1(const int* __restrict__ src, const int* __restrict__ dst, int E,
                        int last, int* __restrict__ deg, int* __restrict__ mark,
                        int* __restrict__ cnt, int2* __restrict__ E3l, int* __restrict__ F2)
{
    int i = blockIdx.x * blockDim.x + threadIdx.x;
    if (i == 0) {
        if (!(atomicOr(&mark[last], M2) & M2)) {
            int q = atomicAdd(&cnt[0], 1);
            if (q < CAP_F2) F2[q] = last;
        }
    }
    if (i >= E) return;
    int d = dst[i];
    atomicAdd(&deg[d], 1);
    if (d == last) {
        int s = src[i];
        int pe = atomicAdd(&cnt[1], 1);
        if (pe < CAP_E3) E3l[pe] = make_int2(s, d);
        if (!(atomicOr(&mark[s], M2) & M2)) {
            int q = atomicAdd(&cnt[0], 1);
            if (q < CAP_F2) F2[q] = s;
        }
    }
}

// ---- k_mark2: F2 self-prop into F1 + edges into M2 nodes -> E2, F1/M1 ----
__global__ void k_mark2(const int* __restrict__ src, const int* __restrict__ dst, int E,
                        int* __restrict__ mark, int* __restrict__ cnt,
                        const int* __restrict__ F2, int* __restrict__ F1,
                        int2* __restrict__ E2l)
{
    int i = blockIdx.x * blockDim.x + threadIdx.x;
    int cF2 = cnt[0]; if (cF2 > CAP_F2) cF2 = CAP_F2;
    if (i < cF2) {
        int v = F2[i];
        if (!(atomicOr(&mark[v], M1) & M1)) {
            int q = atomicAdd(&cnt[2], 1);
            if (q < CAP_F1) F1[q] = v;
        }
    }
    if (i >= E) return;
    int d = dst[i];
    if (mark[d] & M2) {                      // M2 final (set in k_mark1)
        int s = src[i];
        int pe = atomicAdd(&cnt[3], 1);
        if (pe < CAP_E2) E2l[pe] = make_int2(s, d);
        if (!(atomicOr(&mark[s], M1) & M1)) {
            int q = atomicAdd(&cnt[2], 1);
            if (q < CAP_F1) F1[q] = s;
        }
    }
}

// ---- k_gemm1: H1 = x @ W1 for ALL rows; init agg1 = dinv^2*H1 on M1 rows ----
// W1 (64 KB fp32) staged in LDS; one wave per row, __shfl broadcast.
__global__ __launch_bounds__(256) void k_gemm1(
    const float* __restrict__ X, const float* __restrict__ W1,
    const int* __restrict__ mark, const int* __restrict__ deg,
    float* __restrict__ H, float* __restrict__ agg1, int n)
{
    __shared__ float wsm[128][128];
    const int t = threadIdx.x;
    {
        const float4* W4 = (const float4*)W1;
        float4* S4 = (float4*)&wsm[0][0];
        #pragma unroll
        for (int it = 0; it < 16; ++it) S4[it * 256 + t] = W4[it * 256 + t];
    }
    __syncthreads();

    const int wave = t >> 6, lane = t & 63;
    for (int r = blockIdx.x * 4 + wave; r < n; r += gridDim.x * 4) {
        size_t off = (size_t)r * NF;
        float x0 = X[off + lane];
        float x1 = X[off + lane + 64];
        float a0 = 0.f, a1 = 0.f;
        #pragma unroll 16
        for (int k = 0; k < 64; ++k) {
            float xk = __shfl(x0, k);
            a0 += xk * wsm[k][lane];
            a1 += xk * wsm[k][lane + 64];
        }
        #pragma unroll 16
        for (int k = 0; k < 64; ++k) {
            float xk = __shfl(x1, k);
            a0 += xk * wsm[k + 64][lane];
            a1 += xk * wsm[k + 64][lane + 64];
        }
        H[off + lane]      = a0;
        H[off + lane + 64] = a1;
        if (mark[r] & M1) {
            float di = dinv_of(deg, r);
            float s2 = di * di;
            agg1[off + lane]      = a0 * s2;
            agg1[off + lane + 64] = a1 * s2;
        }
    }
}

// ---- k_scatf: scan ALL edges; for dst in M1: agg1[d] += H1[s]*dinv[s]*dinv[d] ----
// Block-local LDS queue: scan 256 edges/iter one-per-thread, then expand matches.
__global__ __launch_bounds__(256) void k_scatf(
    const int* __restrict__ src, const int* __restrict__ dst, int E,
    const int* __restrict__ mark, const int* __restrict__ deg,
    const float* __restrict__ H, float* __restrict__ agg1)
{
    __shared__ int qs[256], qd[256];
    __shared__ float qw[256];
    __shared__ int qn;
    const int t = threadIdx.x;
    const int half = t >> 7, f = t & 127;

    for (int base = blockIdx.x * 256; base < E; base += gridDim.x * 256) {
        if (t == 0) qn = 0;
        __syncthreads();
        int i = base + t;
        if (i < E) {
            int d = dst[i];
            if (mark[d] & M1) {
                int s = src[i];
                int q = atomicAdd(&qn, 1);
                qs[q] = s; qd[q] = d;
                qw[q] = dinv_of(deg, s) * dinv_of(deg, d);
            }
        }
        __syncthreads();
        int m = qn;
        for (int j = half; j < m; j += 2) {
            atomicAdd(&agg1[(size_t)qd[j] * NF + f], H[(size_t)qs[j] * NF + f] * qw[j]);
        }
        __syncthreads();
    }
}

// ---- k_tail1: single block does layers 2+3 and the fc ----
__global__ __launch_bounds__(256) void k_tail1(
    const int* __restrict__ cnt, const int* __restrict__ F1, const int* __restrict__ F2,
    const int2* __restrict__ E2l, const int2* __restrict__ E3l,
    const int* __restrict__ mark, const int* __restrict__ deg,
    const float* __restrict__ agg1, const float* __restrict__ b1,
    const float* __restrict__ W2, const float* __restrict__ b2,
    const float* __restrict__ W3, const float* __restrict__ b3,
    const float* __restrict__ fcW, const float* __restrict__ fcb,
    float* __restrict__ H, float* __restrict__ aggB,
    float* __restrict__ out, int last)
{
    __shared__ float wsm[128][128];
    __shared__ float a3[128];
    const int t = threadIdx.x;
    const int wave = t >> 6, lane = t & 63;

    int cF2 = cnt[0]; if (cF2 > CAP_F2) cF2 = CAP_F2;
    int cE3 = cnt[1]; if (cE3 > CAP_E3) cE3 = CAP_E3;
    int cF1 = cnt[2]; if (cF1 > CAP_F1) cF1 = CAP_F1;
    int cE2 = cnt[3]; if (cE2 > CAP_E2) cE2 = CAP_E2;

    // ---- stage W2, gemm2 over F1: H2[v] = relu(agg1[v]+b1) @ W2 ----
    {
        const float4* W4 = (const float4*)W2;
        float4* S4 = (float4*)&wsm[0][0];
        #pragma unroll
        for (int it = 0; it < 16; ++it) S4[it * 256 + t] = W4[it * 256 + t];
    }
    __syncthreads();
    for (int r = wave; r < cF1; r += 4) {
        int v = F1[r];
        size_t off = (size_t)v * NF;
        float x0 = fmaxf(agg1[off + lane]      + b1[lane],      0.f);
        float x1 = fmaxf(agg1[off + lane + 64] + b1[lane + 64], 0.f);
        float a0 = 0.f, a1 = 0.f;
        #pragma unroll 16
        for (int k = 0; k < 64; ++k) {
            float xk = __shfl(x0, k);
            a0 += xk * wsm[k][lane];
            a1 += xk * wsm[k][lane + 64];
        }
        #pragma unroll 16
        for (int k = 0; k < 64; ++k) {
            float xk = __shfl(x1, k);
            a0 += xk * wsm[k + 64][lane];
            a1 += xk * wsm[k + 64][lane + 64];
        }
        H[off + lane]      = a0;
        H[off + lane + 64] = a1;
        if (mark[v] & M2) {         // every M2 node is in F1 (self-prop)
            float di = dinv_of(deg, v);
            float s2 = di * di;
            aggB[off + lane]      = a0 * s2;
            aggB[off + lane + 64] = a1 * s2;
        }
    }
    __syncthreads();

    // ---- scat2 over E2: aggB[d] += H2[s]*w ----
    {
        const int half = t >> 7, f = t & 127;
        for (int j = half; j < cE2; j += 2) {
            int2 e = E2l[j];
            float w = dinv_of(deg, e.x) * dinv_of(deg, e.y);
            atomicAdd(&aggB[(size_t)e.y * NF + f], H[(size_t)e.x * NF + f] * w);
        }
    }
    __syncthreads();

    // ---- stage W3, gemm3 over F2: H3[v] = relu(aggB[v]+b2) @ W3 ----
    {
        const float4* W4 = (const float4*)W3;
        float4* S4 = (float4*)&wsm[0][0];
        #pragma unroll
        for (int it = 0; it < 16; ++it) S4[it * 256 + t] = W4[it * 256 + t];
    }
    __syncthreads();
    for (int r = wave; r < cF2; r += 4) {
        int v = F2[r];
        size_t off = (size_t)v * NF;
        float x0 = fmaxf(aggB[off + lane]      + b2[lane],      0.f);
        float x1 = fmaxf(aggB[off + lane + 64] + b2[lane + 64], 0.f);
        float a0 = 0.f, a1 = 0.f;
        #pragma unroll 16
        for (int k = 0; k < 64; ++k) {
            float xk = __shfl(x0, k);
            a0 += xk * wsm[k][lane];
            a1 += xk * wsm[k][lane + 64];
        }
        #pragma unroll 16
        for (int k = 0; k < 64; ++k) {
            float xk = __shfl(x1, k);
            a0 += xk * wsm[k + 64][lane];
            a1 += xk * wsm[k + 64][lane + 64];
        }
        H[off + lane]      = a0;   // overwrite H2 row (no longer needed)
        H[off + lane + 64] = a1;
    }
    __syncthreads();

    // ---- scat3 (into a3) + self term + relu(+b3) ----
    if (t < NF) {
        float dl = dinv_of(deg, last);
        float acc = dl * dl * H[(size_t)last * NF + t];
        for (int j = 0; j < cE3; ++j) {
            int2 e = E3l[j];
            float w = dinv_of(deg, e.x) * dl;
            acc += H[(size_t)e.x * NF + t] * w;
        }
        a3[t] = fmaxf(acc + b3[t], 0.f);
    }
    __syncthreads();

    // ---- fc: out = a3 @ fcW + fcb ----
    if (t < OUTF) {
        float acc = fcb[t];
        #pragma unroll 16
        for (int k = 0; k < NF; ++k) acc += a3[k] * fcW[k * OUTF + t];
        out[t] = acc;
    }
}

extern "C" void kernel_launch(void* const* d_in, const int* in_sizes, int n_in,
                              void* d_out, int out_size, void* d_ws, size_t ws_size,
                              hipStream_t stream)
{
    const float* x    = (const float*)d_in[0];
    const int*   ei   = (const int*)d_in[1];
    const float* W1   = (const float*)d_in[2];
    const float* b1   = (const float*)d_in[3];
    const float* W2   = (const float*)d_in[4];
    const float* b2   = (const float*)d_in[5];
    const float* W3   = (const float*)d_in[6];
    const float* b3   = (const float*)d_in[7];
    const float* fcW  = (const float*)d_in[8];
    const float* fcb  = (const float*)d_in[9];
    float* out = (float*)d_out;

    const int n = in_sizes[0] / NF;       // 50000
    const int E = in_sizes[1] / 2;        // 600000
    const int* src = ei;
    const int* dst = ei + E;
    const int last = n - 1;

    char* wp = (char*)d_ws;
    auto alloc = [&](size_t bytes) -> void* {
        void* r = (void*)wp;
        wp += (bytes + 255) & ~(size_t)255;
        return r;
    };

    // zeroed region: deg | mark | cnt (single CP fill)
    int* deg  = (int*)alloc((size_t)n * 4);
    int* mark = (int*)alloc((size_t)n * 4);
    int* cnt  = (int*)alloc(64 * 4);
    size_t zbytes = (char*)wp - (char*)deg;

    int*   F2   = (int*)  alloc(CAP_F2 * 4);
    int2*  E3l  = (int2*) alloc(CAP_E3 * 8);
    int*   F1   = (int*)  alloc(CAP_F1 * 4);
    int2*  E2l  = (int2*) alloc(CAP_E2 * 8);
    float* H    = (float*)alloc((size_t)n * NF * 4);
    float* agg1 = (float*)alloc((size_t)n * NF * 4);
    float* aggB = (float*)alloc((size_t)n * NF * 4);

    const int B  = 256;
    const int EB = (E + B - 1) / B;

    hipMemsetAsync(deg, 0, zbytes, stream);
    k_mark1<<<EB, B, 0, stream>>>(src, dst, E, last, deg, mark, cnt, E3l, F2);
    k_mark2<<<EB, B, 0, stream>>>(src, dst, E, mark, cnt, F2, F1, E2l);
    k_gemm1<<<512, B, 0, stream>>>(x, W1, mark, deg, H, agg1, n);
    k_scatf<<<512, B, 0, stream>>>(src, dst, E, mark, deg, H, agg1);
    k_tail1<<<1, B, 0, stream>>>(cnt, F1, F2, E2l, E3l, mark, deg,
                                 agg1, b1, W2, b2, W3, b3, fcW, fcb,
                                 H, aggB, out, last);
}

// Round 9
// 284.299 us; speedup vs baseline: 1.5727x; 1.3422x over previous
//
#include <hip/hip_runtime.h>

#define NF 128
#define OUTF 64

// mark bits
#define M2 1   // layer-2 frontier: last + its in-neighbors
#define M1 2   // layer-1 frontier: M2 nodes + their in-neighbors

// capacity caps (measured cone ~13 M2 / ~181 M1 nodes; big slack)
#define CAP_F2 4096
#define CAP_E3 8192
#define CAP_F1 65536
#define CAP_E2 131072

// cnt[0]=F2, cnt[1]=E3, cnt[2]=F1, cnt[3]=E2

#define GEMM_BLKS 512
#define MARK_BLKS 1024

__device__ __forceinline__ float dinv_of(const int* deg, int v) {
    return rsqrtf(1.0f + (float)deg[v]);
}

// ---- K1: role-split fused kernel ----
// blocks [0, GEMM_BLKS):          H = x @ W1 for all n rows (W1 in LDS, shfl bcast)
// blocks [GEMM_BLKS, +MARK_BLKS): deg histogram + BFS level 1 (edges into last);
//                                 zero aggB row on each F2 append.
__global__ __launch_bounds__(256) void k_phase1(
    const float* __restrict__ X, const float* __restrict__ W1,
    float* __restrict__ H, int n,
    const int* __restrict__ src, const int* __restrict__ dst, int E, int last,
    int* __restrict__ deg, int* __restrict__ mark, int* __restrict__ cnt,
    int2* __restrict__ E3l, int* __restrict__ F2, float* __restrict__ aggB)
{
    __shared__ float wsm[128][128];
    const int t = threadIdx.x;

    if (blockIdx.x < GEMM_BLKS) {
        // ---------------- gemm1 ----------------
        {
            const float4* W4 = (const float4*)W1;
            float4* S4 = (float4*)&wsm[0][0];
            #pragma unroll
            for (int it = 0; it < 16; ++it) S4[it * 256 + t] = W4[it * 256 + t];
        }
        __syncthreads();
        const int wave = t >> 6, lane = t & 63;
        for (int r = blockIdx.x * 4 + wave; r < n; r += GEMM_BLKS * 4) {
            size_t off = (size_t)r * NF;
            float x0 = X[off + lane];
            float x1 = X[off + lane + 64];
            float a0 = 0.f, a1 = 0.f;
            #pragma unroll 16
            for (int k = 0; k < 64; ++k) {
                float xk = __shfl(x0, k);
                a0 += xk * wsm[k][lane];
                a1 += xk * wsm[k][lane + 64];
            }
            #pragma unroll 16
            for (int k = 0; k < 64; ++k) {
                float xk = __shfl(x1, k);
                a0 += xk * wsm[k + 64][lane];
                a1 += xk * wsm[k + 64][lane + 64];
            }
            H[off + lane]      = a0;
            H[off + lane + 64] = a1;
        }
    } else {
        // ---------------- mark1 ----------------
        const int gtid = (blockIdx.x - GEMM_BLKS) * 256 + t;
        const int gstride = MARK_BLKS * 256;
        if (gtid == 0) {
            if (!(atomicOr(&mark[last], M2) & M2)) {
                int q = atomicAdd(&cnt[0], 1);
                if (q < CAP_F2) {
                    F2[q] = last;
                    float* ab = aggB + (size_t)last * NF;
                    for (int k = 0; k < NF; ++k) ab[k] = 0.f;
                }
            }
        }
        for (int i = gtid; i < E; i += gstride) {
            int d = dst[i];
            atomicAdd(&deg[d], 1);
            if (d == last) {
                int s = src[i];
                int pe = atomicAdd(&cnt[1], 1);
                if (pe < CAP_E3) E3l[pe] = make_int2(s, d);
                if (!(atomicOr(&mark[s], M2) & M2)) {
                    int q = atomicAdd(&cnt[0], 1);
                    if (q < CAP_F2) {
                        F2[q] = s;
                        float* ab = aggB + (size_t)s * NF;
                        for (int k = 0; k < NF; ++k) ab[k] = 0.f;
                    }
                }
            }
        }
    }
}

// ---- K2: mark2: F2 self-prop into F1 + edges into M2 nodes -> E2l, F1/M1.
//      Zero agg1 row on each F1 append. ----
__global__ void k_mark2(const int* __restrict__ src, const int* __restrict__ dst, int E,
                        int* __restrict__ mark, int* __restrict__ cnt,
                        const int* __restrict__ F2, int* __restrict__ F1,
                        int2* __restrict__ E2l, float* __restrict__ agg1)
{
    const int gtid = blockIdx.x * 256 + threadIdx.x;
    const int gstride = gridDim.x * 256;

    int cF2 = cnt[0]; if (cF2 > CAP_F2) cF2 = CAP_F2;
    if (gtid < cF2) {
        int v = F2[gtid];
        if (!(atomicOr(&mark[v], M1) & M1)) {
            int q = atomicAdd(&cnt[2], 1);
            if (q < CAP_F1) {
                F1[q] = v;
                float* ag = agg1 + (size_t)v * NF;
                for (int k = 0; k < NF; ++k) ag[k] = 0.f;
            }
        }
    }
    for (int i = gtid; i < E; i += gstride) {
        int d = dst[i];
        if (mark[d] & M2) {                  // M2 final (set in K1)
            int s = src[i];
            int pe = atomicAdd(&cnt[3], 1);
            if (pe < CAP_E2) E2l[pe] = make_int2(s, d);
            if (!(atomicOr(&mark[s], M1) & M1)) {
                int q = atomicAdd(&cnt[2], 1);
                if (q < CAP_F1) {
                    F1[q] = s;
                    float* ag = agg1 + (size_t)s * NF;
                    for (int k = 0; k < NF; ++k) ag[k] = 0.f;
                }
            }
        }
    }
}

// ---- K3: scatf: scan all edges; dst in M1 -> agg1[d] += H1[s]*dinv[s]*dinv[d] ----
__global__ __launch_bounds__(256) void k_scatf(
    const int* __restrict__ src, const int* __restrict__ dst, int E,
    const int* __restrict__ mark, const int* __restrict__ deg,
    const float* __restrict__ H, float* __restrict__ agg1)
{
    __shared__ int qs[256], qd[256];
    __shared__ float qw[256];
    __shared__ int qn;
    const int t = threadIdx.x;
    const int half = t >> 7, f = t & 127;

    for (int base = blockIdx.x * 256; base < E; base += gridDim.x * 256) {
        if (t == 0) qn = 0;
        __syncthreads();
        int i = base + t;
        if (i < E) {
            int d = dst[i];
            if (mark[d] & M1) {
                int s = src[i];
                int q = atomicAdd(&qn, 1);
                qs[q] = s; qd[q] = d;
                qw[q] = dinv_of(deg, s) * dinv_of(deg, d);
            }
        }
        __syncthreads();
        int m = qn;
        for (int j = half; j < m; j += 2) {
            atomicAdd(&agg1[(size_t)qd[j] * NF + f], H[(size_t)qs[j] * NF + f] * qw[j]);
        }
        __syncthreads();
    }
}

// ---- K4: gemm2 over F1: x = relu(agg1[v] + dinv^2*H1[v] + b1); H[v] = x @ W2 ----
__global__ __launch_bounds__(256) void k_gemm2(
    const int* __restrict__ cnt, const int* __restrict__ F1,
    const float* __restrict__ agg1, const float* __restrict__ b1,
    const float* __restrict__ W2, const int* __restrict__ deg,
    float* __restrict__ H)
{
    __shared__ float wsm[128][128];
    const int t = threadIdx.x;
    {
        const float4* W4 = (const float4*)W2;
        float4* S4 = (float4*)&wsm[0][0];
        #pragma unroll
        for (int it = 0; it < 16; ++it) S4[it * 256 + t] = W4[it * 256 + t];
    }
    __syncthreads();

    int cF1 = cnt[2]; if (cF1 > CAP_F1) cF1 = CAP_F1;
    const int wave = t >> 6, lane = t & 63;
    for (int r = blockIdx.x * 4 + wave; r < cF1; r += gridDim.x * 4) {
        int v = F1[r];
        size_t off = (size_t)v * NF;
        float di = dinv_of(deg, v);
        float s2 = di * di;
        float x0 = fmaxf(agg1[off + lane]      + s2 * H[off + lane]      + b1[lane],      0.f);
        float x1 = fmaxf(agg1[off + lane + 64] + s2 * H[off + lane + 64] + b1[lane + 64], 0.f);
        float a0 = 0.f, a1 = 0.f;
        #pragma unroll 16
        for (int k = 0; k < 64; ++k) {
            float xk = __shfl(x0, k);
            a0 += xk * wsm[k][lane];
            a1 += xk * wsm[k][lane + 64];
        }
        #pragma unroll 16
        for (int k = 0; k < 64; ++k) {
            float xk = __shfl(x1, k);
            a0 += xk * wsm[k + 64][lane];
            a1 += xk * wsm[k + 64][lane + 64];
        }
        H[off + lane]      = a0;   // overwrite H1[v] with H2[v] (self-term already read)
        H[off + lane + 64] = a1;
    }
}

// ---- K5: single-block tail: scat2 + gemm3 + scat3 + fc ----
__global__ __launch_bounds__(256) void k_tail2(
    const int* __restrict__ cnt, const int* __restrict__ F2,
    const int2* __restrict__ E2l, const int2* __restrict__ E3l,
    const int* __restrict__ deg,
    const float* __restrict__ b2, const float* __restrict__ W3,
    const float* __restrict__ b3, const float* __restrict__ fcW,
    const float* __restrict__ fcb,
    float* __restrict__ H, float* __restrict__ aggB,
    float* __restrict__ out, int last)
{
    __shared__ float wsm[128][128];
    __shared__ float a3[NF];
    const int t = threadIdx.x;
    const int wave = t >> 6, lane = t & 63;

    int cF2 = cnt[0]; if (cF2 > CAP_F2) cF2 = CAP_F2;
    int cE3 = cnt[1]; if (cE3 > CAP_E3) cE3 = CAP_E3;
    int cE2 = cnt[3]; if (cE2 > CAP_E2) cE2 = CAP_E2;

    // scat2: aggB[d] += H2[s] * w  (aggB rows zeroed at F2 append in K1)
    {
        const int half = t >> 7, f = t & 127;
        for (int j = half; j < cE2; j += 2) {
            int2 e = E2l[j];
            float w = dinv_of(deg, e.x) * dinv_of(deg, e.y);
            atomicAdd(&aggB[(size_t)e.y * NF + f], H[(size_t)e.x * NF + f] * w);
        }
    }
    __syncthreads();

    // stage W3
    {
        const float4* W4 = (const float4*)W3;
        float4* S4 = (float4*)&wsm[0][0];
        #pragma unroll
        for (int it = 0; it < 16; ++it) S4[it * 256 + t] = W4[it * 256 + t];
    }
    __syncthreads();

    // gemm3 over F2: x = relu(aggB[v] + dinv^2*H2[v] + b2); H[v] = x @ W3
    for (int r = wave; r < cF2; r += 4) {
        int v = F2[r];
        size_t off = (size_t)v * NF;
        float di = dinv_of(deg, v);
        float s2 = di * di;
        float x0 = fmaxf(aggB[off + lane]      + s2 * H[off + lane]      + b2[lane],      0.f);
        float x1 = fmaxf(aggB[off + lane + 64] + s2 * H[off + lane + 64] + b2[lane + 64], 0.f);
        float a0 = 0.f, a1 = 0.f;
        #pragma unroll 16
        for (int k = 0; k < 64; ++k) {
            float xk = __shfl(x0, k);
            a0 += xk * wsm[k][lane];
            a1 += xk * wsm[k][lane + 64];
        }
        #pragma unroll 16
        for (int k = 0; k < 64; ++k) {
            float xk = __shfl(x1, k);
            a0 += xk * wsm[k + 64][lane];
            a1 += xk * wsm[k + 64][lane + 64];
        }
        H[off + lane]      = a0;
        H[off + lane + 64] = a1;
    }
    __syncthreads();

    // scat3 + self term + relu(+b3)
    if (t < NF) {
        float dl = dinv_of(deg, last);
        float acc = dl * dl * H[(size_t)last * NF + t];
        for (int j = 0; j < cE3; ++j) {
            int2 e = E3l[j];
            acc += H[(size_t)e.x * NF + t] * dinv_of(deg, e.x) * dl;
        }
        a3[t] = fmaxf(acc + b3[t], 0.f);
    }
    __syncthreads();

    // fc
    if (t < OUTF) {
        float acc = fcb[t];
        #pragma unroll 16
        for (int k = 0; k < NF; ++k) acc += a3[k] * fcW[k * OUTF + t];
        out[t] = acc;
    }
}

extern "C" void kernel_launch(void* const* d_in, const int* in_sizes, int n_in,
                              void* d_out, int out_size, void* d_ws, size_t ws_size,
                              hipStream_t stream)
{
    const float* x    = (const float*)d_in[0];
    const int*   ei   = (const int*)d_in[1];
    const float* W1   = (const float*)d_in[2];
    const float* b1   = (const float*)d_in[3];
    const float* W2   = (const float*)d_in[4];
    const float* b2   = (const float*)d_in[5];
    const float* W3   = (const float*)d_in[6];
    const float* b3   = (const float*)d_in[7];
    const float* fcW  = (const float*)d_in[8];
    const float* fcb  = (const float*)d_in[9];
    float* out = (float*)d_out;

    const int n = in_sizes[0] / NF;       // 50000
    const int E = in_sizes[1] / 2;        // 600000
    const int* src = ei;
    const int* dst = ei + E;
    const int last = n - 1;

    char* wp = (char*)d_ws;
    auto alloc = [&](size_t bytes) -> void* {
        void* r = (void*)wp;
        wp += (bytes + 255) & ~(size_t)255;
        return r;
    };

    // zeroed region: deg | mark | cnt (single CP fill)
    int* deg  = (int*)alloc((size_t)n * 4);
    int* mark = (int*)alloc((size_t)n * 4);
    int* cnt  = (int*)alloc(64 * 4);
    size_t zbytes = (char*)wp - (char*)deg;

    int*   F2   = (int*)  alloc(CAP_F2 * 4);
    int2*  E3l  = (int2*) alloc(CAP_E3 * 8);
    int*   F1   = (int*)  alloc(CAP_F1 * 4);
    int2*  E2l  = (int2*) alloc(CAP_E2 * 8);
    float* H    = (float*)alloc((size_t)n * NF * 4);
    float* agg1 = (float*)alloc((size_t)n * NF * 4);
    float* aggB = (float*)alloc((size_t)n * NF * 4);

    hipMemsetAsync(deg, 0, zbytes, stream);
    k_phase1<<<GEMM_BLKS + MARK_BLKS, 256, 0, stream>>>(
        x, W1, H, n, src, dst, E, last, deg, mark, cnt, E3l, F2, aggB);
    k_mark2<<<MARK_BLKS, 256, 0, stream>>>(src, dst, E, mark, cnt, F2, F1, E2l, agg1);
    k_scatf<<<512, 256, 0, stream>>>(src, dst, E, mark, deg, H, agg1);
    k_gemm2<<<64, 256, 0, stream>>>(cnt, F1, agg1, b1, W2, deg, H);
    k_tail2<<<1, 256, 0, stream>>>(cnt, F2, E2l, E3l, deg, b2, W3, b3, fcW, fcb,
                                   H, aggB, out, last);
}